// Round 8
// baseline (42.797 us; speedup 1.0000x reference)
//
#include <hip/hip_runtime.h>

#define S_CONST 8
#define EPSF 1e-8f
#define CPW 4          // 64-row chunks per wave
#define WPB 4          // waves per block

struct Samp { int y; int a1[S_CONST]; int a2[S_CONST]; };

__device__ __forceinline__ void gload_lds16(const float* g, float* l) {
    __builtin_amdgcn_global_load_lds(
        (const __attribute__((address_space(1))) void*)g,
        (__attribute__((address_space(3))) void*)l,
        16, 0, 0);   // dwordx4: lane deposits 16B at ldsbase + lane*16
}

// stage one 64-row chunk (64*80B) into this wave's panel via async LDS-DMA
__device__ __forceinline__ void stage(const float* __restrict__ pCS, float* buf,
                                      int base, int B, int lane) {
    const float* src = pCS + (size_t)base * 20;
    const bool full = (base + 64) <= B;
    #pragma unroll
    for (int k = 0; k < 5; ++k) {
        const int g = lane + (k << 6);            // float4 index within chunk
        if (full || base + g / 5 < B)
            gload_lds16(src + (size_t)g * 4, buf + (size_t)k * 256);
    }
}

__device__ __forceinline__ void load_samp(Samp& sm, const int* __restrict__ Y,
                                          const int* __restrict__ s1g,
                                          const int* __restrict__ s2g,
                                          int B, int row, bool inb) {
    if (inb) {
        sm.y = Y[row];
        #pragma unroll
        for (int s = 0; s < S_CONST; ++s) {
            sm.a1[s] = s1g[(size_t)s * B + row];
            sm.a2[s] = s2g[(size_t)s * B + row];
        }
    } else {
        sm.y = -1;
        #pragma unroll
        for (int s = 0; s < S_CONST; ++s) { sm.a1[s] = 0; sm.a2[s] = 0; }
    }
}

// fused log + entropy + gather-select for one element j of one head
__device__ __forceinline__ void elem(int j, float p, const int a[S_CONST],
                                     float g[S_CONST], float& ent) {
    const float lg = __logf(p);
    ent += p * lg;
    #pragma unroll
    for (int s = 0; s < S_CONST; ++s) g[s] = (a[s] == j) ? lg : g[s];
}

__device__ __forceinline__ void compute(const float4& w0, const float4& w1,
                                        const float4& w2, const float4& w3,
                                        const float4& w4, const Samp& sm,
                                        float& ent, float& uniq, float& corr,
                                        float& rloo) {
    float c[S_CONST], csum = 0.f;
    #pragma unroll
    for (int s = 0; s < S_CONST; ++s) {
        c[s] = (sm.a1[s] + sm.a2[s] == sm.y) ? 1.f : 0.f;
        csum += c[s];
    }
    corr += csum;

    {
        int pr[S_CONST];
        #pragma unroll
        for (int s = 0; s < S_CONST; ++s) pr[s] = sm.a1[s] * 10 + sm.a2[s];
        #pragma unroll
        for (int i = 0; i < S_CONST; ++i) {
            bool dup = false;
            #pragma unroll
            for (int j = 0; j < i; ++j) dup = dup || (pr[i] == pr[j]);
            uniq += dup ? 0.f : 1.f;
        }
    }

    float adv[S_CONST];
    #pragma unroll
    for (int s = 0; s < S_CONST; ++s)
        adv[s] = c[s] * (8.0f / 7.0f) - csum * (1.0f / 7.0f);   // c-(csum-c)/7

    float g1[S_CONST];
    #pragma unroll
    for (int s = 0; s < S_CONST; ++s) g1[s] = 0.f;
    elem(0, w0.x, sm.a1, g1, ent); elem(1, w0.y, sm.a1, g1, ent);
    elem(2, w0.z, sm.a1, g1, ent); elem(3, w0.w, sm.a1, g1, ent);
    elem(4, w1.x, sm.a1, g1, ent); elem(5, w1.y, sm.a1, g1, ent);
    elem(6, w1.z, sm.a1, g1, ent); elem(7, w1.w, sm.a1, g1, ent);
    elem(8, w2.x, sm.a1, g1, ent); elem(9, w2.y, sm.a1, g1, ent);
    #pragma unroll
    for (int s = 0; s < S_CONST; ++s) rloo += g1[s] * adv[s];

    float g2[S_CONST];
    #pragma unroll
    for (int s = 0; s < S_CONST; ++s) g2[s] = 0.f;
    elem(0, w2.z, sm.a2, g2, ent); elem(1, w2.w, sm.a2, g2, ent);
    elem(2, w3.x, sm.a2, g2, ent); elem(3, w3.y, sm.a2, g2, ent);
    elem(4, w3.z, sm.a2, g2, ent); elem(5, w3.w, sm.a2, g2, ent);
    elem(6, w4.x, sm.a2, g2, ent); elem(7, w4.y, sm.a2, g2, ent);
    elem(8, w4.z, sm.a2, g2, ent); elem(9, w4.w, sm.a2, g2, ent);
    #pragma unroll
    for (int s = 0; s < S_CONST; ++s) rloo += g2[s] * adv[s];
}

// partials[nblocks]: float4 {ent, uniq, corr, rloo}
__global__ __launch_bounds__(256, 4) void fml_pipe(
        const float* __restrict__ pCS,
        const int* __restrict__ Y,
        const int* __restrict__ s1g,
        const int* __restrict__ s2g,
        float4* __restrict__ partials,
        int B, int nchunks)
{
    __shared__ float pan[WPB][2][64 * 20];   // 2 DMA panels per wave, 40 KiB total
    __shared__ float red[WPB][4];

    const int lane = threadIdx.x & 63;
    const int wv   = threadIdx.x >> 6;
    float* buf0 = pan[wv][0];
    float* buf1 = pan[wv][1];

    const int wid = blockIdx.x * WPB + wv;
    const int c0  = wid * CPW;

    float ent = 0.f, uniq = 0.f, corr = 0.f, rloo = 0.f;
    Samp sm[2];

    // ---- prologue: stage c0->buf0, c1->buf1, samples for c0 ----
    if (c0 < nchunks)     stage(pCS, buf0, c0 << 6, B, lane);
    if (c0 + 1 < nchunks) stage(pCS, buf1, (c0 + 1) << 6, B, lane);
    {
        const int base = c0 << 6;
        const bool inb = (c0 < nchunks) && ((size_t)base + lane < (size_t)B);
        load_samp(sm[0], Y, s1g, s2g, B, base + lane, inb);
    }

    #pragma unroll
    for (int i = 0; i < CPW; ++i) {
        const int cur = i & 1;
        const int c = c0 + i;
        const bool has = c < nchunks;
        const int base = c << 6;
        const bool inb = has && (base + lane < B);

        // read own row from panel (compiler inserts vmcnt wait for the DMA)
        float4 w0, w1, w2, w3, w4;
        if (has) {
            const float4* rp = reinterpret_cast<const float4*>(
                (cur ? buf1 : buf0) + lane * 20);
            w0 = rp[0]; w1 = rp[1]; w2 = rp[2]; w3 = rp[3]; w4 = rp[4];
        }

        // restage this buffer with chunk i+2 (issued now, consumed 1 phase later)
        if (i + 2 < CPW && c0 + i + 2 < nchunks)
            stage(pCS, cur ? buf1 : buf0, (c0 + i + 2) << 6, B, lane);

        // issue next chunk's samples; consumed next iteration
        if (i + 1 < CPW) {
            const int bn = (c0 + i + 1) << 6;
            const bool inbn = (c0 + i + 1 < nchunks) && (bn + lane < B);
            load_samp(sm[(i + 1) & 1], Y, s1g, s2g, B, bn + lane, inbn);
        }

        if (inb) compute(w0, w1, w2, w3, w4, sm[cur], ent, uniq, corr, rloo);
    }

    // ---- 64-lane butterfly ----
    #pragma unroll
    for (int off = 32; off >= 1; off >>= 1) {
        ent  += __shfl_xor(ent,  off);
        uniq += __shfl_xor(uniq, off);
        corr += __shfl_xor(corr, off);
        rloo += __shfl_xor(rloo, off);
    }

    if (lane == 0) {
        red[wv][0] = ent; red[wv][1] = uniq;
        red[wv][2] = corr; red[wv][3] = rloo;
    }
    __syncthreads();
    if (threadIdx.x == 0) {
        float4 p;
        p.x = red[0][0] + red[1][0] + red[2][0] + red[3][0];
        p.y = red[0][1] + red[1][1] + red[2][1] + red[3][1];
        p.z = red[0][2] + red[1][2] + red[2][2] + red[3][2];
        p.w = red[0][3] + red[1][3] + red[2][3] + red[3][3];
        partials[blockIdx.x] = p;
    }
}

__global__ __launch_bounds__(1024) void fml_finalize(
        const float4* __restrict__ partials,
        const float* __restrict__ base_loss,
        float* __restrict__ out, int B, int nblocks)
{
    __shared__ double red[16][4];
    double e = 0, u = 0, cs = 0, rl = 0;
    for (int i = threadIdx.x; i < nblocks; i += 1024) {
        const float4 p = partials[i];
        e += (double)p.x; u += (double)p.y; cs += (double)p.z; rl += (double)p.w;
    }
    #pragma unroll
    for (int off = 32; off >= 1; off >>= 1) {
        e  += __shfl_xor(e,  off);
        u  += __shfl_xor(u,  off);
        cs += __shfl_xor(cs, off);
        rl += __shfl_xor(rl, off);
    }
    const int lane = threadIdx.x & 63;
    const int wave = threadIdx.x >> 6;
    if (lane == 0) { red[wave][0] = e; red[wave][1] = u; red[wave][2] = cs; red[wave][3] = rl; }
    __syncthreads();
    if (threadIdx.x == 0) {
        e = 0; u = 0; cs = 0; rl = 0;
        #pragma unroll
        for (int w = 0; w < 16; ++w) {
            e += red[w][0]; u += red[w][1]; cs += red[w][2]; rl += red[w][3];
        }
        const double dB = (double)B;
        const float entropy_loss = (float)(e / (2.0 * dB));   // = -(ent1+ent2)/2
        const float diversity = (float)(u / dB);
        const float ratio = diversity / 8.0f;                 // max_diversity = 8
        const float diversity_loss = -logf(ratio + EPSF);
        const float sample_acc = (float)(cs / (dB * (double)S_CONST));
        const float rloo_loss  = (float)(-rl / (dB * (double)S_CONST));
        out[0] = base_loss[0] + 0.01f * entropy_loss + 0.1f * diversity_loss;
        out[1] = rloo_loss;
        out[2] = diversity_loss;
        out[3] = sample_acc;
    }
}

extern "C" void kernel_launch(void* const* d_in, const int* in_sizes, int n_in,
                              void* d_out, int out_size, void* d_ws, size_t ws_size,
                              hipStream_t stream) {
    const float* pCS       = (const float*)d_in[0];
    const float* base_loss = (const float*)d_in[1];
    const int*   Y         = (const int*)d_in[2];
    const int*   s1        = (const int*)d_in[3];
    const int*   s2        = (const int*)d_in[4];
    float* out = (float*)d_out;
    const int B = in_sizes[2];

    const int nchunks = (B + 63) >> 6;
    const int waves   = (nchunks + CPW - 1) / CPW;
    const int blocks  = (waves + WPB - 1) / WPB;   // 1024 at B=1M -> 4 blocks/CU exact

    float4* partials = (float4*)d_ws;              // blocks*16B = 16 KB at B=1M

    fml_pipe<<<blocks, 256, 0, stream>>>(pCS, Y, s1, s2, partials, B, nchunks);
    fml_finalize<<<1, 1024, 0, stream>>>(partials, base_loss, out, B, blocks);
}